// Round 4
// baseline (348.071 us; speedup 1.0000x reference)
//
#include <hip/hip_runtime.h>
#include <math.h>

typedef _Float16 half8 __attribute__((ext_vector_type(8)));
typedef _Float16 half4 __attribute__((ext_vector_type(4)));
typedef float f32x4 __attribute__((ext_vector_type(4)));

#define HDIM 128
#define W12_HALFS 49152                     // W1p (32768) + W2p (16384) in LDS
#define SCR_HALFS 2048                      // per-wave scratch: 16 rows x 128 halfs, XOR-swizzled
#define LDS_HALFS (W12_HALFS + 8 * SCR_HALFS)   // 65536 halfs
#define LDS_BYTES (LDS_HALFS * 2)               // 131072 B -> 1 block/CU, comfortable

// ---------------------------------------------------------------------------
// Prep: x (N x 128 fp32) -> fp16; pack W1/W2/W3 into MFMA A-operand frag order
// (transposed GEMM, A = W^T):
//   frag(ct,ks), lane: A[m=ct*16+(lane&15)][k=ks*32+(lane>>4)*8+j] = W[k][m]
// ---------------------------------------------------------------------------
__global__ __launch_bounds__(256) void prep_kernel(
    const float* __restrict__ x,  const float* __restrict__ W1,
    const float* __restrict__ W2, const float* __restrict__ W3,
    _Float16* __restrict__ xh,  _Float16* __restrict__ W1p,
    _Float16* __restrict__ W2p, _Float16* __restrict__ W3p, int NF)
{
    int bid = blockIdx.x;
    if (bid < 32) {
        int t = bid * 256 + threadIdx.x;   // 0..8191
        const float* W; _Float16* Wp; int KS; int u;
        if (t < 4096)      { W = W1; Wp = W1p; KS = 8; u = t; }          // 256x128
        else if (t < 6144) { W = W2; Wp = W2p; KS = 4; u = t - 4096; }   // 128x128
        else               { W = W3; Wp = W3p; KS = 4; u = t - 6144; }   // 128x128
        int lane = u & 63;
        int fk   = u >> 6;            // ct*KS + ks
        int ks   = fk % KS;
        int ct   = fk / KS;
        int m    = ct * 16 + (lane & 15);
        int k0   = ks * 32 + (lane >> 4) * 8;
        half8 v;
        #pragma unroll
        for (int j = 0; j < 8; ++j) v[j] = (_Float16)W[(k0 + j) * HDIM + m];
        *(half8*)(Wp + (size_t)u * 8) = v;
    } else {
        long i = (long)(bid - 32) * 2048 + (long)threadIdx.x * 8;
        if (i + 8 <= (long)NF) {
            const float4* xf = (const float4*)(x + i);
            float4 f0 = xf[0], f1 = xf[1];
            half8 v;
            v[0] = (_Float16)f0.x; v[1] = (_Float16)f0.y;
            v[2] = (_Float16)f0.z; v[3] = (_Float16)f0.w;
            v[4] = (_Float16)f1.x; v[5] = (_Float16)f1.y;
            v[6] = (_Float16)f1.z; v[7] = (_Float16)f1.w;
            *(half8*)(xh + i) = v;
        }
    }
}

// ---------------------------------------------------------------------------
// Epilogue: relu(acc + bias) -> fp16 scratch (16 edges x 128 h, 128-half rows
// with XOR-16B-chunk swizzle by row&7 -> b64 writes & b128 reads both ~2-way,
// free), pull back next layer's B-frags. Resets acc.
// ---------------------------------------------------------------------------
__device__ __forceinline__ void epi_extract(
    f32x4 (&acc)[4][8], const float* __restrict__ bias,
    _Float16* __restrict__ scr, int l15, int quad, half8 (&bh)[4][4])
{
    const int r7   = l15 & 7;
    const int rowb = l15 * 128;
    const int wch  = quad >> 1;          // write chunk sub-index
    const int woff = (quad & 1) << 2;    // half offset within 16B chunk
    float4 bv[8];
    #pragma unroll
    for (int ct = 0; ct < 8; ++ct)
        bv[ct] = *(const float4*)(bias + ct * 16 + quad * 4);
    #pragma unroll
    for (int nt = 0; nt < 4; ++nt) {
        #pragma unroll
        for (int ct = 0; ct < 8; ++ct) {
            half4 h;
            h[0] = (_Float16)fmaxf(acc[nt][ct][0] + bv[ct].x, 0.f);
            h[1] = (_Float16)fmaxf(acc[nt][ct][1] + bv[ct].y, 0.f);
            h[2] = (_Float16)fmaxf(acc[nt][ct][2] + bv[ct].z, 0.f);
            h[3] = (_Float16)fmaxf(acc[nt][ct][3] + bv[ct].w, 0.f);
            *(half4*)(scr + rowb + ((((ct * 2 + wch)) ^ r7) << 3) + woff) = h;
            acc[nt][ct] = f32x4{0.f, 0.f, 0.f, 0.f};
        }
        #pragma unroll
        for (int ks = 0; ks < 4; ++ks)
            bh[nt][ks] = *(const half8*)(scr + rowb + (((ks * 4 + quad) ^ r7) << 3));
    }
}

__device__ __forceinline__ void layer_mfma(
    f32x4 (&acc)[4][8], const _Float16* __restrict__ Wl,
    half8 (&bh)[4][4], int lane)
{
    #pragma unroll
    for (int ks = 0; ks < 4; ++ks) {
        half8 aw[8];
        #pragma unroll
        for (int ct = 0; ct < 8; ++ct)
            aw[ct] = *(const half8*)(Wl + ((size_t)((ct * 4 + ks) * 64 + lane)) * 8);
        #pragma unroll
        for (int nt = 0; nt < 4; ++nt)
            #pragma unroll
            for (int ct = 0; ct < 8; ++ct)
                acc[nt][ct] = __builtin_amdgcn_mfma_f32_16x16x32_f16(
                    aw[ct], bh[nt][ks], acc[nt][ct], 0, 0, 0);
    }
}

// ---------------------------------------------------------------------------
// Persistent fused MLP, transposed GEMM D[hidden][edge] = W^T x ef^T.
// 512 thr = 8 waves/block, 131 KB LDS -> 1 block/CU, VGPR ~224 -> 2 waves/SIMD
// (the round-3 point: cross-wave latency hiding). Each wave owns 64 edges/tile.
// W1,W2 from LDS; W3 from global (L2-hot).
// ---------------------------------------------------------------------------
__global__ __launch_bounds__(512, 2) void edge_mlp_kernel(
    const int* __restrict__ ei, const _Float16* __restrict__ xh,
    const _Float16* __restrict__ w12,    // W1p|W2p contiguous, 49152 halfs
    const _Float16* __restrict__ W3p,    // 16384 halfs, stays in global
    const float* __restrict__ b1, const float* __restrict__ b2,
    const float* __restrict__ b3, const float* __restrict__ W4,
    const float* __restrict__ b4, float* __restrict__ out, int E)
{
    extern __shared__ _Float16 lds[];
    {   // stage W1p+W2p (98304 B) once per persistent block
        float4* dst = (float4*)lds;
        const float4* src = (const float4*)w12;
        #pragma unroll
        for (int i = 0; i < 12; ++i)
            dst[i * 512 + threadIdx.x] = src[i * 512 + threadIdx.x];
    }
    __syncthreads();

    const int tid  = threadIdx.x;
    const int wave = tid >> 6;
    const int lane = tid & 63;
    const int l15  = lane & 15;
    const int quad = lane >> 4;

    const _Float16* W1l = lds;
    const _Float16* W2l = lds + 32768;
    _Float16* scr = lds + W12_HALFS + wave * SCR_HALFS;

    const int ntiles = (E + 511) >> 9;
    const float b4v = b4[0];

    for (int t = blockIdx.x; t < ntiles; t += gridDim.x) {
        const int base = t * 512 + wave * 64;

        // ---- gather layer-1 B-frags: B[k=concat-feat][n=edge] ----
        half8 bef[4][8];
        #pragma unroll
        for (int nt = 0; nt < 4; ++nt) {
            const int row = min(base + nt * 16 + l15, E - 1);
            const _Float16* pi = xh + (size_t)ei[row] * HDIM;
            const _Float16* pj = xh + (size_t)ei[E + row] * HDIM;
            #pragma unroll
            for (int ks = 0; ks < 4; ++ks) {
                bef[nt][ks]     = *(const half8*)(pi + ks * 32 + quad * 8);
                bef[nt][4 + ks] = *(const half8*)(pj + ks * 32 + quad * 8);
            }
        }

        f32x4 acc[4][8];
        #pragma unroll
        for (int nt = 0; nt < 4; ++nt)
            #pragma unroll
            for (int ct = 0; ct < 8; ++ct) acc[nt][ct] = f32x4{0.f, 0.f, 0.f, 0.f};

        // ---- layer 1: K=256, weights from LDS ----
        #pragma unroll
        for (int ks = 0; ks < 8; ++ks) {
            half8 aw[8];
            #pragma unroll
            for (int ct = 0; ct < 8; ++ct)
                aw[ct] = *(const half8*)(W1l + ((size_t)((ct * 8 + ks) * 64 + lane)) * 8);
            #pragma unroll
            for (int nt = 0; nt < 4; ++nt)
                #pragma unroll
                for (int ct = 0; ct < 8; ++ct)
                    acc[nt][ct] = __builtin_amdgcn_mfma_f32_16x16x32_f16(
                        aw[ct], bef[nt][ks], acc[nt][ct], 0, 0, 0);
        }

        half8 bh[4][4];
        epi_extract(acc, b1, scr, l15, quad, bh);     // h1 -> B-frags
        layer_mfma(acc, W2l, bh, lane);               // layer 2 (LDS weights)
        epi_extract(acc, b2, scr, l15, quad, bh);     // h2 -> B-frags
        layer_mfma(acc, W3p, bh, lane);               // layer 3 (global weights, L2)

        // ---- layer 4: per-edge dot over hidden + sigmoid ----
        #pragma unroll
        for (int nt = 0; nt < 4; ++nt) {
            float s = 0.f;
            #pragma unroll
            for (int ct = 0; ct < 8; ++ct) {
                float4 b3v = *(const float4*)(b3 + ct * 16 + quad * 4);
                float4 w4v = *(const float4*)(W4 + ct * 16 + quad * 4);
                s += fmaxf(acc[nt][ct][0] + b3v.x, 0.f) * w4v.x;
                s += fmaxf(acc[nt][ct][1] + b3v.y, 0.f) * w4v.y;
                s += fmaxf(acc[nt][ct][2] + b3v.z, 0.f) * w4v.z;
                s += fmaxf(acc[nt][ct][3] + b3v.w, 0.f) * w4v.w;
            }
            s += __shfl_xor(s, 16, 64);   // sum the 4 quads (same l15)
            s += __shfl_xor(s, 32, 64);
            const int row = base + nt * 16 + l15;
            if (quad == 0 && row < E)
                out[row] = 1.f / (1.f + __expf(-(s + b4v)));
        }
    }
}

// ---------------------------------------------------------------------------
extern "C" void kernel_launch(void* const* d_in, const int* in_sizes, int n_in,
                              void* d_out, int out_size, void* d_ws, size_t ws_size,
                              hipStream_t stream)
{
    const float* x  = (const float*)d_in[0];
    const int*   ei = (const int*)d_in[1];
    const float* W1 = (const float*)d_in[2];
    const float* b1 = (const float*)d_in[3];
    const float* W2 = (const float*)d_in[4];
    const float* b2 = (const float*)d_in[5];
    const float* W3 = (const float*)d_in[6];
    const float* b3 = (const float*)d_in[7];
    const float* W4 = (const float*)d_in[8];
    const float* b4 = (const float*)d_in[9];
    float* out = (float*)d_out;

    const int NF = in_sizes[0];    // N*F = 12,800,000
    const int E  = out_size;       // 625,000

    // ws layout (halfs): [ xh : NF ][ W1p : 32768 ][ W2p : 16384 ][ W3p : 16384 ]
    _Float16* xh  = (_Float16*)d_ws;
    _Float16* W1p = xh + NF;
    _Float16* W2p = W1p + 32768;
    _Float16* W3p = W2p + 16384;

    const int xblocks = (NF + 2047) / 2048;
    prep_kernel<<<32 + xblocks, 256, 0, stream>>>(x, W1, W2, W3, xh, W1p, W2p, W3p, NF);

    (void)hipFuncSetAttribute((const void*)edge_mlp_kernel,
                              hipFuncAttributeMaxDynamicSharedMemorySize, LDS_BYTES);
    edge_mlp_kernel<<<256, 512, LDS_BYTES, stream>>>(ei, xh, W1p, W3p,
                                                     b1, b2, b3, W4, b4, out, E);
}

// Round 5
// 281.498 us; speedup vs baseline: 1.2365x; 1.2365x over previous
//
#include <hip/hip_runtime.h>
#include <math.h>

typedef _Float16 half8 __attribute__((ext_vector_type(8)));
typedef _Float16 half4 __attribute__((ext_vector_type(4)));
typedef float f32x4 __attribute__((ext_vector_type(4)));

#define HDIM 128
#define W12_HALFS 49152                     // W1p (32768) + W2p (16384) in LDS
#define SCR_HALFS 2048                      // per-wave scratch: 16 rows x 128 halfs, XOR-swizzled
#define LDS_HALFS (W12_HALFS + 8 * SCR_HALFS)   // 65536 halfs
#define LDS_BYTES (LDS_HALFS * 2)               // 131072 B -> 1 block/CU

// ---------------------------------------------------------------------------
// Prep: x (N x 128 fp32) -> fp16; pack W1/W2/W3 into MFMA A-operand frag order
// (transposed GEMM, A = W^T):
//   frag(ct,ks), lane: A[m=ct*16+(lane&15)][k=ks*32+(lane>>4)*8+j] = W[k][m]
// ---------------------------------------------------------------------------
__global__ __launch_bounds__(256) void prep_kernel(
    const float* __restrict__ x,  const float* __restrict__ W1,
    const float* __restrict__ W2, const float* __restrict__ W3,
    _Float16* __restrict__ xh,  _Float16* __restrict__ W1p,
    _Float16* __restrict__ W2p, _Float16* __restrict__ W3p, int NF)
{
    int bid = blockIdx.x;
    if (bid < 32) {
        int t = bid * 256 + threadIdx.x;   // 0..8191
        const float* W; _Float16* Wp; int KS; int u;
        if (t < 4096)      { W = W1; Wp = W1p; KS = 8; u = t; }          // 256x128
        else if (t < 6144) { W = W2; Wp = W2p; KS = 4; u = t - 4096; }   // 128x128
        else               { W = W3; Wp = W3p; KS = 4; u = t - 6144; }   // 128x128
        int lane = u & 63;
        int fk   = u >> 6;            // ct*KS + ks
        int ks   = fk % KS;
        int ct   = fk / KS;
        int m    = ct * 16 + (lane & 15);
        int k0   = ks * 32 + (lane >> 4) * 8;
        half8 v;
        #pragma unroll
        for (int j = 0; j < 8; ++j) v[j] = (_Float16)W[(k0 + j) * HDIM + m];
        *(half8*)(Wp + (size_t)u * 8) = v;
    } else {
        long i = (long)(bid - 32) * 2048 + (long)threadIdx.x * 8;
        if (i + 8 <= (long)NF) {
            const float4* xf = (const float4*)(x + i);
            float4 f0 = xf[0], f1 = xf[1];
            half8 v;
            v[0] = (_Float16)f0.x; v[1] = (_Float16)f0.y;
            v[2] = (_Float16)f0.z; v[3] = (_Float16)f0.w;
            v[4] = (_Float16)f1.x; v[5] = (_Float16)f1.y;
            v[6] = (_Float16)f1.z; v[7] = (_Float16)f1.w;
            *(half8*)(xh + i) = v;
        }
    }
}

// ---------------------------------------------------------------------------
// Epilogue: relu(acc + bias) -> fp16 scratch (16 edges x 128 h, 128-half rows
// with XOR-16B-chunk swizzle by row&7), pull back next layer's B-frags.
// Resets acc. (Correctness-verified in rounds 2/4.)
// ---------------------------------------------------------------------------
__device__ __forceinline__ void epi_extract(
    f32x4 (&acc)[4][8], const float* __restrict__ bias,
    _Float16* __restrict__ scr, int l15, int quad, half8 (&bh)[4][4])
{
    const int r7   = l15 & 7;
    const int rowb = l15 * 128;
    const int wch  = quad >> 1;          // write chunk sub-index
    const int woff = (quad & 1) << 2;    // half offset within 16B chunk
    #pragma unroll
    for (int nt = 0; nt < 4; ++nt) {
        #pragma unroll
        for (int ct = 0; ct < 8; ++ct) {
            const float4 bv = *(const float4*)(bias + ct * 16 + quad * 4);
            half4 h;
            h[0] = (_Float16)fmaxf(acc[nt][ct][0] + bv.x, 0.f);
            h[1] = (_Float16)fmaxf(acc[nt][ct][1] + bv.y, 0.f);
            h[2] = (_Float16)fmaxf(acc[nt][ct][2] + bv.z, 0.f);
            h[3] = (_Float16)fmaxf(acc[nt][ct][3] + bv.w, 0.f);
            *(half4*)(scr + rowb + ((((ct * 2 + wch)) ^ r7) << 3) + woff) = h;
            acc[nt][ct] = f32x4{0.f, 0.f, 0.f, 0.f};
        }
        #pragma unroll
        for (int ks = 0; ks < 4; ++ks)
            bh[nt][ks] = *(const half8*)(scr + rowb + (((ks * 4 + quad) ^ r7) << 3));
    }
}

__device__ __forceinline__ void layer_mfma(
    f32x4 (&acc)[4][8], const _Float16* __restrict__ Wl,
    half8 (&bh)[4][4], int lane)
{
    #pragma unroll
    for (int ks = 0; ks < 4; ++ks) {
        half8 aw[8];
        #pragma unroll
        for (int ct = 0; ct < 8; ++ct)
            aw[ct] = *(const half8*)(Wl + ((ct * 4 + ks) * 64 + lane) * 8);
        #pragma unroll
        for (int nt = 0; nt < 4; ++nt)
            #pragma unroll
            for (int ct = 0; ct < 8; ++ct)
                acc[nt][ct] = __builtin_amdgcn_mfma_f32_16x16x32_f16(
                    aw[ct], bh[nt][ks], acc[nt][ct], 0, 0, 0);
    }
}

// ---------------------------------------------------------------------------
// Persistent fused MLP, transposed GEMM D[hidden][edge] = W^T x ef^T.
// 512 thr = 8 waves/block, 131 KB LDS -> 1 block/CU.
// amdgpu_waves_per_eu(2) pins the VGPR budget at 256/wave -> 2 waves/SIMD.
// Layer-1 B-frags are gathered with a 1-deep per-ks pipeline (32 regs held,
// not 128) so the kernel fits the 256 budget without spill.
// ---------------------------------------------------------------------------
__global__ __launch_bounds__(512) __attribute__((amdgpu_waves_per_eu(2)))
void edge_mlp_kernel(
    const int* __restrict__ ei, const _Float16* __restrict__ xh,
    const _Float16* __restrict__ w12,    // W1p|W2p contiguous, 49152 halfs
    const _Float16* __restrict__ W3p,    // 16384 halfs, stays in global (L2)
    const float* __restrict__ b1, const float* __restrict__ b2,
    const float* __restrict__ b3, const float* __restrict__ W4,
    const float* __restrict__ b4, float* __restrict__ out, int E)
{
    extern __shared__ _Float16 lds[];
    {   // stage W1p+W2p (98304 B) once per persistent block
        float4* dst = (float4*)lds;
        const float4* src = (const float4*)w12;
        #pragma unroll
        for (int i = 0; i < 12; ++i)
            dst[i * 512 + threadIdx.x] = src[i * 512 + threadIdx.x];
    }
    __syncthreads();

    const int tid  = threadIdx.x;
    const int wave = tid >> 6;
    const int lane = tid & 63;
    const int l15  = lane & 15;
    const int quad = lane >> 4;

    const _Float16* W1l = lds;
    const _Float16* W2l = lds + 32768;
    _Float16* scr = lds + W12_HALFS + wave * SCR_HALFS;

    const int ntiles = (E + 511) >> 9;
    const float b4v = b4[0];

    for (int t = blockIdx.x; t < ntiles; t += gridDim.x) {
        const int base = t * 512 + wave * 64;

        // per-nt gather base pointers (quad offset folded in)
        const _Float16* pp[4][2];
        #pragma unroll
        for (int nt = 0; nt < 4; ++nt) {
            const int row = min(base + nt * 16 + l15, E - 1);
            pp[nt][0] = xh + (size_t)ei[row] * HDIM + quad * 8;
            pp[nt][1] = xh + (size_t)ei[E + row] * HDIM + quad * 8;
        }

        f32x4 acc[4][8];
        #pragma unroll
        for (int nt = 0; nt < 4; ++nt)
            #pragma unroll
            for (int ct = 0; ct < 8; ++ct) acc[nt][ct] = f32x4{0.f, 0.f, 0.f, 0.f};

        // ---- layer 1: K=256, weights from LDS, gathered B pipelined per-ks
        half8 bcur[4], bnxt[4];
        #pragma unroll
        for (int nt = 0; nt < 4; ++nt) bcur[nt] = *(const half8*)(pp[nt][0]);

        #pragma unroll
        for (int ks = 0; ks < 8; ++ks) {
            if (ks < 7) {
                const int kn = ks + 1;
                #pragma unroll
                for (int nt = 0; nt < 4; ++nt)
                    bnxt[nt] = *(const half8*)(pp[nt][kn >> 2] + (kn & 3) * 32);
            }
            half8 aw[8];
            #pragma unroll
            for (int ct = 0; ct < 8; ++ct)
                aw[ct] = *(const half8*)(W1l + ((ct * 8 + ks) * 64 + lane) * 8);
            #pragma unroll
            for (int nt = 0; nt < 4; ++nt)
                #pragma unroll
                for (int ct = 0; ct < 8; ++ct)
                    acc[nt][ct] = __builtin_amdgcn_mfma_f32_16x16x32_f16(
                        aw[ct], bcur[nt], acc[nt][ct], 0, 0, 0);
            #pragma unroll
            for (int nt = 0; nt < 4; ++nt) bcur[nt] = bnxt[nt];
        }

        half8 bh[4][4];
        epi_extract(acc, b1, scr, l15, quad, bh);     // h1 -> B-frags
        layer_mfma(acc, W2l, bh, lane);               // layer 2 (LDS weights)
        epi_extract(acc, b2, scr, l15, quad, bh);     // h2 -> B-frags
        layer_mfma(acc, W3p, bh, lane);               // layer 3 (global weights, L2)

        // ---- layer 4: per-edge dot over hidden + sigmoid ----
        #pragma unroll
        for (int nt = 0; nt < 4; ++nt) {
            float s = 0.f;
            #pragma unroll
            for (int ct = 0; ct < 8; ++ct) {
                float4 b3v = *(const float4*)(b3 + ct * 16 + quad * 4);
                float4 w4v = *(const float4*)(W4 + ct * 16 + quad * 4);
                s += fmaxf(acc[nt][ct][0] + b3v.x, 0.f) * w4v.x;
                s += fmaxf(acc[nt][ct][1] + b3v.y, 0.f) * w4v.y;
                s += fmaxf(acc[nt][ct][2] + b3v.z, 0.f) * w4v.z;
                s += fmaxf(acc[nt][ct][3] + b3v.w, 0.f) * w4v.w;
            }
            s += __shfl_xor(s, 16, 64);   // sum the 4 quads (same l15)
            s += __shfl_xor(s, 32, 64);
            const int row = base + nt * 16 + l15;
            if (quad == 0 && row < E)
                out[row] = 1.f / (1.f + __expf(-(s + b4v)));
        }
    }
}

// ---------------------------------------------------------------------------
extern "C" void kernel_launch(void* const* d_in, const int* in_sizes, int n_in,
                              void* d_out, int out_size, void* d_ws, size_t ws_size,
                              hipStream_t stream)
{
    const float* x  = (const float*)d_in[0];
    const int*   ei = (const int*)d_in[1];
    const float* W1 = (const float*)d_in[2];
    const float* b1 = (const float*)d_in[3];
    const float* W2 = (const float*)d_in[4];
    const float* b2 = (const float*)d_in[5];
    const float* W3 = (const float*)d_in[6];
    const float* b3 = (const float*)d_in[7];
    const float* W4 = (const float*)d_in[8];
    const float* b4 = (const float*)d_in[9];
    float* out = (float*)d_out;

    const int NF = in_sizes[0];    // N*F = 12,800,000
    const int E  = out_size;       // 625,000

    // ws layout (halfs): [ xh : NF ][ W1p : 32768 ][ W2p : 16384 ][ W3p : 16384 ]
    _Float16* xh  = (_Float16*)d_ws;
    _Float16* W1p = xh + NF;
    _Float16* W2p = W1p + 32768;
    _Float16* W3p = W2p + 16384;

    const int xblocks = (NF + 2047) / 2048;
    prep_kernel<<<32 + xblocks, 256, 0, stream>>>(x, W1, W2, W3, xh, W1p, W2p, W3p, NF);

    (void)hipFuncSetAttribute((const void*)edge_mlp_kernel,
                              hipFuncAttributeMaxDynamicSharedMemorySize, LDS_BYTES);
    edge_mlp_kernel<<<256, 512, LDS_BYTES, stream>>>(ei, xh, W1p, W3p,
                                                     b1, b2, b3, W4, b4, out, E);
}